// Round 1
// baseline (31379.477 us; speedup 1.0000x reference)
//
#include <hip/hip_runtime.h>
#include <math.h>

// Problem constants (PointerNet): B=256, Li=512, Lo=128, C=16, E=128, H=256
//
// Single persistent kernel, grid 256 WGs x 256 threads (1 WG/CU).
// WG w: phase (a) identity (bi = w>>4 batch tile of 16, dj = w&15 dim tile of 16);
//       phase (c) identity (batch row b = w).
// Thread t: b_local = t>>4, dim_local = t&15; owns LSTM cell state c[b,d] in a register.
// Cross-WG data (h ping-pong, enc_proj, ptr, flags) moves through L3 via sc0/sc1
// coherent loads/stores; weights/inputs stay L2/L1-cached (no cache-flushing fences).

typedef float vf4 __attribute__((ext_vector_type(4)));
typedef int   vi4 __attribute__((ext_vector_type(4)));

__device__ __forceinline__ void ld4_sc1(const vf4* p, vf4& a0, vf4& a1, vf4& a2, vf4& a3) {
  asm volatile(
      "global_load_dwordx4 %0, %4, off sc0 sc1\n\t"
      "global_load_dwordx4 %1, %5, off sc0 sc1\n\t"
      "global_load_dwordx4 %2, %6, off sc0 sc1\n\t"
      "global_load_dwordx4 %3, %7, off sc0 sc1\n\t"
      "s_waitcnt vmcnt(0)"
      : "=&v"(a0), "=&v"(a1), "=&v"(a2), "=&v"(a3)
      : "v"(p), "v"(p + 1), "v"(p + 2), "v"(p + 3)
      : "memory");
}

// tanh via exp identity: exact identity, only rounding error (~1e-7 abs).
__device__ __forceinline__ float tanh_fast(float x) {
  float e = __expf(2.0f * x);
  return 1.0f - 2.0f * __builtin_amdgcn_rcpf(e + 1.0f);
}

// Grid barrier: flag per WG, monotonically increasing generation.
// ws is re-poisoned 0xAA before every launch -> flags start negative (signed int),
// so generation counting from 1 needs no initialization phase.
__device__ __forceinline__ void gridbar(int* flags, int g) {
  __syncthreads();  // drains vmcnt for all waves -> all sc1 data stores are at L3
  if (threadIdx.x == 0)
    __hip_atomic_store(&flags[blockIdx.x], g, __ATOMIC_RELAXED, __HIP_MEMORY_SCOPE_AGENT);
  if (threadIdx.x < 64) {  // only wave 0 polls; lane L covers flags[4L..4L+3]
    const vi4* fp = (const vi4*)flags + threadIdx.x;
    for (;;) {
      vi4 f;
      asm volatile("global_load_dwordx4 %0, %1, off sc0 sc1\n\ts_waitcnt vmcnt(0)"
                   : "=v"(f) : "v"(fp) : "memory");
      if (f.x >= g && f.y >= g && f.z >= g && f.w >= g) break;
      __builtin_amdgcn_s_sleep(8);
    }
  }
  __syncthreads();
}

__device__ __forceinline__ void load_htile(const float* src, float* lds_h_, int tid) {
  // 16 rows x 256 floats, thread loads 16 contiguous floats (4x b128, sc1-coherent)
  int r = tid >> 4;
  int k0 = (tid & 15) << 4;
  vf4 a0, a1, a2, a3;
  ld4_sc1((const vf4*)(src + (r << 8) + k0), a0, a1, a2, a3);
  vf4* dst = (vf4*)(lds_h_ + r * 260 + k0);  // row pad 260 keeps b128 alignment + breaks bank aliasing
  dst[0] = a0; dst[1] = a1; dst[2] = a2; dst[3] = a3;
}

__global__ __launch_bounds__(256, 1) void pointer_net_kernel(
    const float* __restrict__ inputs,  // [256,512,16]
    const float* __restrict__ emb_W,   // [128,16]
    const float* __restrict__ emb_b,   // [128]
    const float* __restrict__ eWih,    // [1024,128]
    const float* __restrict__ eWhh,    // [1024,256]
    const float* __restrict__ eb,      // [1024]
    const float* __restrict__ dWih,    // [1024,128]
    const float* __restrict__ dWhh,    // [1024,256]
    const float* __restrict__ db,      // [1024]
    const float* __restrict__ W1,      // [256,256]
    const float* __restrict__ W2,      // [256,256]
    const float* __restrict__ Vv,      // [256]
    const float* __restrict__ d0,      // [128]
    float* __restrict__ out,           // logits [256,512,128] then pointers [256,128] (as float)
    float* __restrict__ encp,          // ws: [256,512,256]
    float* __restrict__ h_buf,         // ws: [2,256,256]
    int* __restrict__ ptr_buf,         // ws: [256]
    int* __restrict__ flags)           // ws: [256]
{
  __shared__ float lds_h[16 * 260];
  __shared__ float lds_wxe[16 * 64];  // fused enc input weights [c][dim_local*4+gate]
  __shared__ float lds_wxd[16 * 64];  // fused dec input weights
  __shared__ float lds_sc[512];
  __shared__ float lds_de[256];
  __shared__ float lds_hr[256];

  const int tid = threadIdx.x;
  const int wgy = blockIdx.x;
  const int bi = wgy >> 4, dj = wgy & 15;
  const int bl = tid >> 4, dl = tid & 15;
  const int b = (bi << 4) + bl;  // this thread's batch row (phase a)
  const int d = (dj << 4) + dl;  // this thread's hidden dim (phase a)
  const int lane = tid & 63;
  const int wv = tid >> 6;

  // Purge possibly-stale (poisoned) lines from this XCD's L2 once.
  asm volatile("buffer_inv sc1\n\ts_waitcnt vmcnt(0)" ::: "memory");

  // ---- init: fused input weights Wen/Wde = (Wih @ emb_W) slices into LDS ----
  for (int idx = tid; idx < 1024; idx += 256) {
    int c = idx >> 6, jj = idx & 63;                  // jj = dim_local*4 + gate
    int j = ((jj & 3) << 8) + (dj << 4) + (jj >> 2);  // gate*256 + dj*16 + dim_local
    float se = 0.f, sd = 0.f;
    const float* er = eWih + (size_t)j * 128;
    const float* dr = dWih + (size_t)j * 128;
    for (int e = 0; e < 128; ++e) {
      float ew = emb_W[(e << 4) + c];
      se += er[e] * ew;
      sd += dr[e] * ew;
    }
    lds_wxe[idx] = se;
    lds_wxd[idx] = sd;
  }
  // per-thread biases / decoder step-0 input projection
  float benr[4], dber[4], dbemb[4], g0r[4];
  for (int g = 0; g < 4; ++g) {
    int j = (g << 8) + d;
    const float* er = eWih + (size_t)j * 128;
    const float* dr = dWih + (size_t)j * 128;
    float s1 = 0.f, s2 = 0.f, s3 = 0.f;
    for (int e = 0; e < 128; ++e) {
      s1 += er[e] * emb_b[e];
      s2 += dr[e] * emb_b[e];
      s3 += dr[e] * d0[e];
    }
    benr[g] = eb[j] + s1;  // encoder: x always embedded
    dber[g] = db[j];       // decoder: raw bias
    dbemb[g] = s2;         // decoder: + emb_b part when x is embedded (t>0)
    g0r[g] = s3;           // decoder t=0: dec_input0 @ dWih^T
  }
  vf4 v4 = *((const vf4*)Vv + lane);  // attention V fragment (lane*4..+3)

  float c_reg = 0.0f;
  __hip_atomic_store(&h_buf[(b << 8) + d], 0.0f, __ATOMIC_RELAXED, __HIP_MEMORY_SCOPE_AGENT);

  int gen = 0;
  gridbar(flags, ++gen);  // h_buf[0] zeros visible everywhere

  const float* er0 = eWhh + (size_t)((0 << 8) + d) * 256;
  const float* er1 = eWhh + (size_t)((1 << 8) + d) * 256;
  const float* er2 = eWhh + (size_t)((2 << 8) + d) * 256;
  const float* er3 = eWhh + (size_t)((3 << 8) + d) * 256;
  const float* w1r = W1 + (size_t)d * 256;

  // ===================== ENCODER (513 iterations) =====================
  // iter t: lds_h <- h_t;  encp row (t-1) = h_t @ W1^T;  if t<512: gates -> h_{t+1}
  for (int t = 0; t <= 512; ++t) {
    const int pr = t & 1;
    load_htile(h_buf + pr * 65536 + ((bi << 4) << 8), lds_h, tid);
    __syncthreads();

    float a0 = benr[0], a1 = benr[1], a2 = benr[2], a3 = benr[3], ae = 0.0f;
    if (t < 512) {
      const float* xp = inputs + (size_t)(((b << 9) + t) << 4);
      for (int c = 0; c < 16; c += 4) {
        vf4 xv = *(const vf4*)(xp + c);
        vf4 wx0 = *(const vf4*)(lds_wxe + ((c + 0) << 6) + (dl << 2));
        vf4 wx1 = *(const vf4*)(lds_wxe + ((c + 1) << 6) + (dl << 2));
        vf4 wx2 = *(const vf4*)(lds_wxe + ((c + 2) << 6) + (dl << 2));
        vf4 wx3 = *(const vf4*)(lds_wxe + ((c + 3) << 6) + (dl << 2));
        a0 += xv.x * wx0.x + xv.y * wx1.x + xv.z * wx2.x + xv.w * wx3.x;
        a1 += xv.x * wx0.y + xv.y * wx1.y + xv.z * wx2.y + xv.w * wx3.y;
        a2 += xv.x * wx0.z + xv.y * wx1.z + xv.z * wx2.z + xv.w * wx3.z;
        a3 += xv.x * wx0.w + xv.y * wx1.w + xv.z * wx2.w + xv.w * wx3.w;
      }
    }
    const float* hrow = lds_h + bl * 260;
    for (int k = 0; k < 256; k += 4) {
      vf4 h4 = *(const vf4*)(hrow + k);
      vf4 wi = *(const vf4*)(er0 + k);
      vf4 wf = *(const vf4*)(er1 + k);
      vf4 wg = *(const vf4*)(er2 + k);
      vf4 wo = *(const vf4*)(er3 + k);
      vf4 q1 = *(const vf4*)(w1r + k);
      a0 += h4.x * wi.x + h4.y * wi.y + h4.z * wi.z + h4.w * wi.w;
      a1 += h4.x * wf.x + h4.y * wf.y + h4.z * wf.z + h4.w * wf.w;
      a2 += h4.x * wg.x + h4.y * wg.y + h4.z * wg.z + h4.w * wg.w;
      a3 += h4.x * wo.x + h4.y * wo.y + h4.z * wo.z + h4.w * wo.w;
      ae += h4.x * q1.x + h4.y * q1.y + h4.z * q1.z + h4.w * q1.w;
    }
    if (t > 0) {
      float* ep = encp + ((size_t)((b << 9) + (t - 1)) << 8) + d;
      __hip_atomic_store(ep, ae, __ATOMIC_RELAXED, __HIP_MEMORY_SCOPE_AGENT);
    }
    if (t < 512) {
      float ig = 1.0f / (1.0f + expf(-a0));
      float fg = 1.0f / (1.0f + expf(-a1));
      float gg = tanhf(a2);
      float og = 1.0f / (1.0f + expf(-a3));
      c_reg = fg * c_reg + ig * gg;
      float hn = og * tanhf(c_reg);
      __hip_atomic_store(&h_buf[(pr ^ 1) * 65536 + (b << 8) + d], hn,
                         __ATOMIC_RELAXED, __HIP_MEMORY_SCOPE_AGENT);
    }
    gridbar(flags, ++gen);
  }

  // ===================== DECODER (128 steps, 2 barriers each) =====================
  const float* dr0 = dWhh + (size_t)((0 << 8) + d) * 256;
  const float* dr1 = dWhh + (size_t)((1 << 8) + d) * 256;
  const float* dr2 = dWhh + (size_t)((2 << 8) + d) * 256;
  const float* dr3 = dWhh + (size_t)((3 << 8) + d) * 256;

  for (int t = 0; t < 128; ++t) {
    const int pr = t & 1;
    // ---- (a) LSTM step, (bi,dj) decomposition ----
    load_htile(h_buf + pr * 65536 + ((bi << 4) << 8), lds_h, tid);
    __syncthreads();

    float a0 = dber[0], a1 = dber[1], a2 = dber[2], a3 = dber[3];
    if (t == 0) {
      a0 += g0r[0]; a1 += g0r[1]; a2 += g0r[2]; a3 += g0r[3];
    } else {
      a0 += dbemb[0]; a1 += dbemb[1]; a2 += dbemb[2]; a3 += dbemb[3];
      int pidx = __hip_atomic_load(&ptr_buf[b], __ATOMIC_RELAXED, __HIP_MEMORY_SCOPE_AGENT);
      const float* xp = inputs + (size_t)(((b << 9) + pidx) << 4);
      for (int c = 0; c < 16; c += 4) {
        vf4 xv = *(const vf4*)(xp + c);
        vf4 wx0 = *(const vf4*)(lds_wxd + ((c + 0) << 6) + (dl << 2));
        vf4 wx1 = *(const vf4*)(lds_wxd + ((c + 1) << 6) + (dl << 2));
        vf4 wx2 = *(const vf4*)(lds_wxd + ((c + 2) << 6) + (dl << 2));
        vf4 wx3 = *(const vf4*)(lds_wxd + ((c + 3) << 6) + (dl << 2));
        a0 += xv.x * wx0.x + xv.y * wx1.x + xv.z * wx2.x + xv.w * wx3.x;
        a1 += xv.x * wx0.y + xv.y * wx1.y + xv.z * wx2.y + xv.w * wx3.y;
        a2 += xv.x * wx0.z + xv.y * wx1.z + xv.z * wx2.z + xv.w * wx3.z;
        a3 += xv.x * wx0.w + xv.y * wx1.w + xv.z * wx2.w + xv.w * wx3.w;
      }
    }
    {
      const float* hrow = lds_h + bl * 260;
      for (int k = 0; k < 256; k += 4) {
        vf4 h4 = *(const vf4*)(hrow + k);
        vf4 wi = *(const vf4*)(dr0 + k);
        vf4 wf = *(const vf4*)(dr1 + k);
        vf4 wg = *(const vf4*)(dr2 + k);
        vf4 wo = *(const vf4*)(dr3 + k);
        a0 += h4.x * wi.x + h4.y * wi.y + h4.z * wi.z + h4.w * wi.w;
        a1 += h4.x * wf.x + h4.y * wf.y + h4.z * wf.z + h4.w * wf.w;
        a2 += h4.x * wg.x + h4.y * wg.y + h4.z * wg.z + h4.w * wg.w;
        a3 += h4.x * wo.x + h4.y * wo.y + h4.z * wo.z + h4.w * wo.w;
      }
      float ig = 1.0f / (1.0f + expf(-a0));
      float fg = 1.0f / (1.0f + expf(-a1));
      float gg = tanhf(a2);
      float og = 1.0f / (1.0f + expf(-a3));
      c_reg = fg * c_reg + ig * gg;
      float hn = og * tanhf(c_reg);
      __hip_atomic_store(&h_buf[(pr ^ 1) * 65536 + (b << 8) + d], hn,
                         __ATOMIC_RELAXED, __HIP_MEMORY_SCOPE_AGENT);
    }
    gridbar(flags, ++gen);

    // ---- (c) attention scores + argmax; this WG owns batch row wgy ----
    {
      float hv = __hip_atomic_load(&h_buf[(pr ^ 1) * 65536 + (wgy << 8) + tid],
                                   __ATOMIC_RELAXED, __HIP_MEMORY_SCOPE_AGENT);
      lds_hr[tid] = hv;
      __syncthreads();
      // dec_term[d=tid] = h_new[b] . W2[d,:]
      float a = 0.0f;
      const float* w2r = W2 + (size_t)tid * 256;
      for (int k = 0; k < 256; k += 4) {
        vf4 h4 = *(const vf4*)(lds_hr + k);  // broadcast
        vf4 q = *(const vf4*)(w2r + k);
        a += h4.x * q.x + h4.y * q.y + h4.z * q.z + h4.w * q.w;
      }
      lds_de[tid] = a;
      __syncthreads();

      vf4 d4 = *((const vf4*)lds_de + lane);
      // each wave handles li = wv, wv+4, ... (128 rows); lane covers h = lane*4..+3
      const float* bse = encp + ((size_t)wgy << 17) + (wv << 8);
      vf4 A[8], Bv[8];
#pragma unroll
      for (int j = 0; j < 8; ++j)
        A[j] = *((const vf4*)(bse + ((size_t)j << 10)) + lane);
      for (int ch = 0; ch < 16; ++ch) {
        if (ch < 15) {
#pragma unroll
          for (int j = 0; j < 8; ++j)
            Bv[j] = *((const vf4*)(bse + ((size_t)((ch + 1) * 8 + j) << 10)) + lane);
        }
#pragma unroll
        for (int j = 0; j < 8; ++j) {
          int i = ch * 8 + j;
          int li = wv + (i << 2);
          vf4 e4 = A[j];
          float s = v4.x * tanh_fast(e4.x + d4.x)
                  + v4.y * tanh_fast(e4.y + d4.y)
                  + v4.z * tanh_fast(e4.z + d4.z)
                  + v4.w * tanh_fast(e4.w + d4.w);
#pragma unroll
          for (int off = 32; off; off >>= 1) s += __shfl_down(s, off);
          if (lane == 0) {
            lds_sc[li] = s;
            out[(size_t)(((wgy << 9) + li) << 7) + t] = s;  // logits[b][li][t]
          }
        }
#pragma unroll
        for (int j = 0; j < 8; ++j) A[j] = Bv[j];
      }
      __syncthreads();

      // argmax over 512 scores, first-index tie-break (matches np.argmax)
      if (tid < 64) {
        float bs = -3.402823466e38f;
        int bix = 0;
        for (int i = 0; i < 8; ++i) {
          int idx = (i << 6) + tid;
          float s = lds_sc[idx];
          if (s > bs || (s == bs && idx < bix)) { bs = s; bix = idx; }
        }
#pragma unroll
        for (int off = 32; off; off >>= 1) {
          float os = __shfl_down(bs, off);
          int oi = __shfl_down(bix, off);
          if (os > bs || (os == bs && oi < bix)) { bs = os; bix = oi; }
        }
        if (tid == 0) {
          __hip_atomic_store(&ptr_buf[wgy], bix, __ATOMIC_RELAXED, __HIP_MEMORY_SCOPE_AGENT);
          out[(size_t)16777216 + (wgy << 7) + t] = (float)bix;  // pointers[b][t]
        }
      }
    }
    gridbar(flags, ++gen);
  }
}

extern "C" void kernel_launch(void* const* d_in, const int* in_sizes, int n_in,
                              void* d_out, int out_size, void* d_ws, size_t ws_size,
                              hipStream_t stream) {
  (void)in_sizes; (void)n_in; (void)out_size;
  const float* inputs = (const float*)d_in[0];
  const float* emb_W  = (const float*)d_in[1];
  const float* emb_b  = (const float*)d_in[2];
  const float* eWih   = (const float*)d_in[3];
  const float* eWhh   = (const float*)d_in[4];
  const float* eb     = (const float*)d_in[5];
  const float* dWih   = (const float*)d_in[6];
  const float* dWhh   = (const float*)d_in[7];
  const float* db     = (const float*)d_in[8];
  const float* W1     = (const float*)d_in[9];
  const float* W2     = (const float*)d_in[10];
  const float* Vv     = (const float*)d_in[11];
  const float* d0     = (const float*)d_in[12];

  float* out = (float*)d_out;
  // ws layout: encp [256*512*256] | h_buf [2*256*256] | ptr_buf [256] | flags [256]
  float* encp   = (float*)d_ws;
  float* h_buf  = encp + 33554432;
  int*   ptrb   = (int*)(h_buf + 131072);
  int*   flags  = ptrb + 256;

  size_t need = (size_t)(33554432 + 131072) * 4 + 512 * 4;
  if (ws_size < need) return;  // insufficient workspace: fail cleanly (no OOB writes)

  hipLaunchKernelGGL(pointer_net_kernel, dim3(256), dim3(256), 0, stream,
                     inputs, emb_W, emb_b, eWih, eWhh, eb, dWih, dWhh, db,
                     W1, W2, Vv, d0, out, encp, h_buf, ptrb, flags);
}

// Round 2
// 13501.602 us; speedup vs baseline: 2.3241x; 2.3241x over previous
//
#include <hip/hip_runtime.h>
#include <math.h>

// PointerNet: B=256, Li=512, Lo=128, C=16, E=128, H=256
// Persistent kernel, 256 WGs x 256 threads (1 WG/CU), grid barrier via flags.
// v2: per-WG recurrent weights staged in LDS (stride-260 padded rows);
//     enc_proj decoder reads use plain cached loads (written once w/ sc1,
//     read only afterwards -> no stale-copy hazard); batched logits stores.

typedef float vf4 __attribute__((ext_vector_type(4)));
typedef int   vi4 __attribute__((ext_vector_type(4)));

__device__ __forceinline__ void ld4_sc1(const vf4* p, vf4& a0, vf4& a1, vf4& a2, vf4& a3) {
  asm volatile(
      "global_load_dwordx4 %0, %4, off sc0 sc1\n\t"
      "global_load_dwordx4 %1, %5, off sc0 sc1\n\t"
      "global_load_dwordx4 %2, %6, off sc0 sc1\n\t"
      "global_load_dwordx4 %3, %7, off sc0 sc1\n\t"
      "s_waitcnt vmcnt(0)"
      : "=&v"(a0), "=&v"(a1), "=&v"(a2), "=&v"(a3)
      : "v"(p), "v"(p + 1), "v"(p + 2), "v"(p + 3)
      : "memory");
}

__device__ __forceinline__ float tanh_fast(float x) {
  float e = __expf(2.0f * x);
  return 1.0f - 2.0f * __builtin_amdgcn_rcpf(e + 1.0f);
}

// Grid barrier: per-WG flag, monotone generation (ws poisoned 0xAA -> negative).
__device__ __forceinline__ void gridbar(int* flags, int g) {
  __syncthreads();
  if (threadIdx.x == 0)
    __hip_atomic_store(&flags[blockIdx.x], g, __ATOMIC_RELAXED, __HIP_MEMORY_SCOPE_AGENT);
  if (threadIdx.x < 64) {
    const vi4* fp = (const vi4*)flags + threadIdx.x;
    for (;;) {
      vi4 f;
      asm volatile("global_load_dwordx4 %0, %1, off sc0 sc1\n\ts_waitcnt vmcnt(0)"
                   : "=v"(f) : "v"(fp) : "memory");
      if (f.x >= g && f.y >= g && f.z >= g && f.w >= g) break;
      __builtin_amdgcn_s_sleep(2);
    }
  }
  __syncthreads();
}

__device__ __forceinline__ void load_htile(const float* src, float* lds_h_, int tid) {
  int r = tid >> 4;
  int k0 = (tid & 15) << 4;
  vf4 a0, a1, a2, a3;
  ld4_sc1((const vf4*)(src + (r << 8) + k0), a0, a1, a2, a3);
  vf4* dst = (vf4*)(lds_h_ + r * 260 + k0);
  dst[0] = a0; dst[1] = a1; dst[2] = a2; dst[3] = a3;
}

__global__ __launch_bounds__(256, 1) void pointer_net_kernel(
    const float* __restrict__ inputs,  // [256,512,16]
    const float* __restrict__ emb_W,   // [128,16]
    const float* __restrict__ emb_b,   // [128]
    const float* __restrict__ eWih,    // [1024,128]
    const float* __restrict__ eWhh,    // [1024,256]
    const float* __restrict__ eb,      // [1024]
    const float* __restrict__ dWih,    // [1024,128]
    const float* __restrict__ dWhh,    // [1024,256]
    const float* __restrict__ db,      // [1024]
    const float* __restrict__ W1,      // [256,256]
    const float* __restrict__ W2,      // [256,256]
    const float* __restrict__ Vv,      // [256]
    const float* __restrict__ d0,      // [128]
    float* __restrict__ out,           // logits [256,512,128] then pointers [256,128]
    float* __restrict__ encp,          // ws: [256,512,256]
    float* __restrict__ h_buf,         // ws: [2,256,256]
    int* __restrict__ ptr_buf,         // ws: [256]
    int* __restrict__ flags)           // ws: [256]
{
  // recurrent weights: rows g*16+dl (g=0..3 gates), 64+dl (W1); stride 260 pads
  // banks so 16 dl-rows land on 2-way-aliased banks (free per m136).
  __shared__ float lds_w[80 * 260];   // 83.2 KB
  __shared__ float lds_h[16 * 260];   // 16.6 KB
  __shared__ float lds_wx[2][1024];   // fused input weights enc/dec, 8 KB
  __shared__ float lds_sc[512];
  __shared__ float lds_de[256];
  __shared__ float lds_hr[256];

  const int tid = threadIdx.x;
  const int wgy = blockIdx.x;
  const int bi = wgy >> 4, dj = wgy & 15;
  const int bl = tid >> 4, dl = tid & 15;
  const int b = (bi << 4) + bl;
  const int d = (dj << 4) + dl;
  const int lane = tid & 63;
  const int wv = tid >> 6;

  asm volatile("buffer_inv sc1\n\ts_waitcnt vmcnt(0)" ::: "memory");

  // ---- stage encoder recurrent weights + W1 rows into LDS (once) ----
  for (int i = tid; i < 80 * 64; i += 256) {
    int row = i >> 6, kq = (i & 63) << 2;
    const float* src;
    if (row < 64)
      src = eWhh + ((size_t)((row >> 4) << 8) + (dj << 4) + (row & 15)) * 256 + kq;
    else
      src = W1 + ((size_t)(dj << 4) + (row - 64)) * 256 + kq;
    *(vf4*)(lds_w + row * 260 + kq) = *(const vf4*)src;
  }

  // ---- fused input weights (Wih @ emb_W) for this WG's 16 dims ----
  for (int idx = tid; idx < 1024; idx += 256) {
    int c = idx >> 6, jj = idx & 63;                  // jj = dl*4+gate
    int j = ((jj & 3) << 8) + (dj << 4) + (jj >> 2);  // gate*256 + dj*16 + dl
    float se = 0.f, sd = 0.f;
    const float* er = eWih + (size_t)j * 128;
    const float* dr = dWih + (size_t)j * 128;
    for (int e = 0; e < 128; ++e) {
      float ew = emb_W[(e << 4) + c];
      se += er[e] * ew;
      sd += dr[e] * ew;
    }
    lds_wx[0][idx] = se;
    lds_wx[1][idx] = sd;
  }
  float benr[4], dber[4], dbemb[4], g0r[4];
  for (int g = 0; g < 4; ++g) {
    int j = (g << 8) + d;
    const float* er = eWih + (size_t)j * 128;
    const float* dr = dWih + (size_t)j * 128;
    float s1 = 0.f, s2 = 0.f, s3 = 0.f;
    for (int e = 0; e < 128; ++e) {
      s1 += er[e] * emb_b[e];
      s2 += dr[e] * emb_b[e];
      s3 += dr[e] * d0[e];
    }
    benr[g] = eb[j] + s1;
    dber[g] = db[j];
    dbemb[g] = s2;
    g0r[g] = s3;
  }
  vf4 v4 = *((const vf4*)Vv + lane);

  float c_reg = 0.0f;
  __hip_atomic_store(&h_buf[(b << 8) + d], 0.0f, __ATOMIC_RELAXED, __HIP_MEMORY_SCOPE_AGENT);

  int gen = 0;
  gridbar(flags, ++gen);

  const float* w0 = lds_w + dl * 260;  // gate i row; +4160 per gate, +16640 = W1

  // ===================== ENCODER (513 iterations) =====================
  for (int t = 0; t <= 512; ++t) {
    const int pr = t & 1;
    load_htile(h_buf + pr * 65536 + ((bi << 4) << 8), lds_h, tid);
    __syncthreads();

    float a0 = benr[0], a1 = benr[1], a2 = benr[2], a3 = benr[3], ae = 0.0f;
    if (t < 512) {
      const float* xp = inputs + (size_t)(((b << 9) + t) << 4);
      for (int c = 0; c < 16; c += 4) {
        vf4 xv = *(const vf4*)(xp + c);
        vf4 wx0 = *(const vf4*)(&lds_wx[0][((c + 0) << 6) + (dl << 2)]);
        vf4 wx1 = *(const vf4*)(&lds_wx[0][((c + 1) << 6) + (dl << 2)]);
        vf4 wx2 = *(const vf4*)(&lds_wx[0][((c + 2) << 6) + (dl << 2)]);
        vf4 wx3 = *(const vf4*)(&lds_wx[0][((c + 3) << 6) + (dl << 2)]);
        a0 += xv.x * wx0.x + xv.y * wx1.x + xv.z * wx2.x + xv.w * wx3.x;
        a1 += xv.x * wx0.y + xv.y * wx1.y + xv.z * wx2.y + xv.w * wx3.y;
        a2 += xv.x * wx0.z + xv.y * wx1.z + xv.z * wx2.z + xv.w * wx3.z;
        a3 += xv.x * wx0.w + xv.y * wx1.w + xv.z * wx2.w + xv.w * wx3.w;
      }
    }
    const float* hrow = lds_h + bl * 260;
#pragma unroll 4
    for (int k = 0; k < 256; k += 4) {
      vf4 h4 = *(const vf4*)(hrow + k);
      vf4 wi = *(const vf4*)(w0 + k);
      vf4 wf = *(const vf4*)(w0 + 4160 + k);
      vf4 wg = *(const vf4*)(w0 + 8320 + k);
      vf4 wo = *(const vf4*)(w0 + 12480 + k);
      vf4 q1 = *(const vf4*)(w0 + 16640 + k);
      a0 += h4.x * wi.x + h4.y * wi.y + h4.z * wi.z + h4.w * wi.w;
      a1 += h4.x * wf.x + h4.y * wf.y + h4.z * wf.z + h4.w * wf.w;
      a2 += h4.x * wg.x + h4.y * wg.y + h4.z * wg.z + h4.w * wg.w;
      a3 += h4.x * wo.x + h4.y * wo.y + h4.z * wo.z + h4.w * wo.w;
      ae += h4.x * q1.x + h4.y * q1.y + h4.z * q1.z + h4.w * q1.w;
    }
    if (t > 0) {
      float* ep = encp + ((size_t)((b << 9) + (t - 1)) << 8) + d;
      __hip_atomic_store(ep, ae, __ATOMIC_RELAXED, __HIP_MEMORY_SCOPE_AGENT);
    }
    if (t < 512) {
      float ig = 1.0f / (1.0f + expf(-a0));
      float fg = 1.0f / (1.0f + expf(-a1));
      float gg = tanhf(a2);
      float og = 1.0f / (1.0f + expf(-a3));
      c_reg = fg * c_reg + ig * gg;
      float hn = og * tanhf(c_reg);
      __hip_atomic_store(&h_buf[(pr ^ 1) * 65536 + (b << 8) + d], hn,
                         __ATOMIC_RELAXED, __HIP_MEMORY_SCOPE_AGENT);
    }
    gridbar(flags, ++gen);
  }

  // ---- stage decoder recurrent weights over the gate rows (W1 row dead) ----
  for (int i = tid; i < 64 * 64; i += 256) {
    int row = i >> 6, kq = (i & 63) << 2;
    *(vf4*)(lds_w + row * 260 + kq) =
        *(const vf4*)(dWhh + ((size_t)((row >> 4) << 8) + (dj << 4) + (row & 15)) * 256 + kq);
  }
  __syncthreads();

  // ===================== DECODER (128 steps) =====================
  for (int t = 0; t < 128; ++t) {
    const int pr = t & 1;
    load_htile(h_buf + pr * 65536 + ((bi << 4) << 8), lds_h, tid);
    __syncthreads();

    float a0 = dber[0], a1 = dber[1], a2 = dber[2], a3 = dber[3];
    if (t == 0) {
      a0 += g0r[0]; a1 += g0r[1]; a2 += g0r[2]; a3 += g0r[3];
    } else {
      a0 += dbemb[0]; a1 += dbemb[1]; a2 += dbemb[2]; a3 += dbemb[3];
      int pidx = __hip_atomic_load(&ptr_buf[b], __ATOMIC_RELAXED, __HIP_MEMORY_SCOPE_AGENT);
      const float* xp = inputs + (size_t)(((b << 9) + pidx) << 4);
      for (int c = 0; c < 16; c += 4) {
        vf4 xv = *(const vf4*)(xp + c);
        vf4 wx0 = *(const vf4*)(&lds_wx[1][((c + 0) << 6) + (dl << 2)]);
        vf4 wx1 = *(const vf4*)(&lds_wx[1][((c + 1) << 6) + (dl << 2)]);
        vf4 wx2 = *(const vf4*)(&lds_wx[1][((c + 2) << 6) + (dl << 2)]);
        vf4 wx3 = *(const vf4*)(&lds_wx[1][((c + 3) << 6) + (dl << 2)]);
        a0 += xv.x * wx0.x + xv.y * wx1.x + xv.z * wx2.x + xv.w * wx3.x;
        a1 += xv.x * wx0.y + xv.y * wx1.y + xv.z * wx2.y + xv.w * wx3.y;
        a2 += xv.x * wx0.z + xv.y * wx1.z + xv.z * wx2.z + xv.w * wx3.z;
        a3 += xv.x * wx0.w + xv.y * wx1.w + xv.z * wx2.w + xv.w * wx3.w;
      }
    }
    {
      const float* hrow = lds_h + bl * 260;
#pragma unroll 4
      for (int k = 0; k < 256; k += 4) {
        vf4 h4 = *(const vf4*)(hrow + k);
        vf4 wi = *(const vf4*)(w0 + k);
        vf4 wf = *(const vf4*)(w0 + 4160 + k);
        vf4 wg = *(const vf4*)(w0 + 8320 + k);
        vf4 wo = *(const vf4*)(w0 + 12480 + k);
        a0 += h4.x * wi.x + h4.y * wi.y + h4.z * wi.z + h4.w * wi.w;
        a1 += h4.x * wf.x + h4.y * wf.y + h4.z * wf.z + h4.w * wf.w;
        a2 += h4.x * wg.x + h4.y * wg.y + h4.z * wg.z + h4.w * wg.w;
        a3 += h4.x * wo.x + h4.y * wo.y + h4.z * wo.z + h4.w * wo.w;
      }
      float ig = 1.0f / (1.0f + expf(-a0));
      float fg = 1.0f / (1.0f + expf(-a1));
      float gg = tanhf(a2);
      float og = 1.0f / (1.0f + expf(-a3));
      c_reg = fg * c_reg + ig * gg;
      float hn = og * tanhf(c_reg);
      __hip_atomic_store(&h_buf[(pr ^ 1) * 65536 + (b << 8) + d], hn,
                         __ATOMIC_RELAXED, __HIP_MEMORY_SCOPE_AGENT);
    }
    gridbar(flags, ++gen);

    // ---- attention scores + argmax; WG owns batch row wgy ----
    {
      float hv = __hip_atomic_load(&h_buf[(pr ^ 1) * 65536 + (wgy << 8) + tid],
                                   __ATOMIC_RELAXED, __HIP_MEMORY_SCOPE_AGENT);
      lds_hr[tid] = hv;
      __syncthreads();
      float a = 0.0f;
      const float* w2r = W2 + (size_t)tid * 256;
      for (int k = 0; k < 256; k += 4) {
        vf4 h4 = *(const vf4*)(lds_hr + k);
        vf4 q = *(const vf4*)(w2r + k);
        a += h4.x * q.x + h4.y * q.y + h4.z * q.z + h4.w * q.w;
      }
      lds_de[tid] = a;
      __syncthreads();

      vf4 d4 = *((const vf4*)lds_de + lane);
      // plain cached loads: encp written once (sc1 write-through) during the
      // encoder, read-only afterwards -> no stale copy can exist in L1/L2.
      const float* bse = encp + ((size_t)wgy << 17) + (wv << 8);
      vf4 A[8], Bv[8];
#pragma unroll
      for (int j = 0; j < 8; ++j)
        A[j] = *((const vf4*)(bse + ((size_t)j << 10)) + lane);
      for (int ch = 0; ch < 16; ++ch) {
        if (ch < 15) {
#pragma unroll
          for (int j = 0; j < 8; ++j)
            Bv[j] = *((const vf4*)(bse + ((size_t)((ch + 1) * 8 + j) << 10)) + lane);
        }
#pragma unroll
        for (int j = 0; j < 8; ++j) {
          int li = wv + (((ch << 3) + j) << 2);
          vf4 e4 = A[j];
          float s = v4.x * tanh_fast(e4.x + d4.x)
                  + v4.y * tanh_fast(e4.y + d4.y)
                  + v4.z * tanh_fast(e4.z + d4.z)
                  + v4.w * tanh_fast(e4.w + d4.w);
#pragma unroll
          for (int off = 32; off; off >>= 1) s += __shfl_down(s, off);
          if (lane == 0) lds_sc[li] = s;
        }
#pragma unroll
        for (int j = 0; j < 8; ++j) A[j] = Bv[j];
      }
      __syncthreads();

      // batched logits scatter (2 stores/thread)
      for (int i = tid; i < 512; i += 256)
        out[(size_t)(((wgy << 9) + i) << 7) + t] = lds_sc[i];

      // argmax, first-index tie-break
      if (tid < 64) {
        float bs = -3.402823466e38f;
        int bix = 0;
        for (int i = 0; i < 8; ++i) {
          int idx = (i << 6) + tid;
          float s = lds_sc[idx];
          if (s > bs || (s == bs && idx < bix)) { bs = s; bix = idx; }
        }
#pragma unroll
        for (int off = 32; off; off >>= 1) {
          float os = __shfl_down(bs, off);
          int oi = __shfl_down(bix, off);
          if (os > bs || (os == bs && oi < bix)) { bs = os; bix = oi; }
        }
        if (tid == 0) {
          __hip_atomic_store(&ptr_buf[wgy], bix, __ATOMIC_RELAXED, __HIP_MEMORY_SCOPE_AGENT);
          out[(size_t)16777216 + (wgy << 7) + t] = (float)bix;
        }
      }
    }
    gridbar(flags, ++gen);
  }
}

extern "C" void kernel_launch(void* const* d_in, const int* in_sizes, int n_in,
                              void* d_out, int out_size, void* d_ws, size_t ws_size,
                              hipStream_t stream) {
  (void)in_sizes; (void)n_in; (void)out_size;
  const float* inputs = (const float*)d_in[0];
  const float* emb_W  = (const float*)d_in[1];
  const float* emb_b  = (const float*)d_in[2];
  const float* eWih   = (const float*)d_in[3];
  const float* eWhh   = (const float*)d_in[4];
  const float* eb     = (const float*)d_in[5];
  const float* dWih   = (const float*)d_in[6];
  const float* dWhh   = (const float*)d_in[7];
  const float* db     = (const float*)d_in[8];
  const float* W1     = (const float*)d_in[9];
  const float* W2     = (const float*)d_in[10];
  const float* Vv     = (const float*)d_in[11];
  const float* d0     = (const float*)d_in[12];

  float* out = (float*)d_out;
  float* encp   = (float*)d_ws;
  float* h_buf  = encp + 33554432;
  int*   ptrb   = (int*)(h_buf + 131072);
  int*   flags  = ptrb + 256;

  size_t need = (size_t)(33554432 + 131072) * 4 + 512 * 4;
  if (ws_size < need) return;

  hipLaunchKernelGGL(pointer_net_kernel, dim3(256), dim3(256), 0, stream,
                     inputs, emb_W, emb_b, eWih, eWhh, eb, dWih, dWhh, db,
                     W1, W2, Vv, d0, out, encp, h_buf, ptrb, flags);
}